// Round 13
// baseline (366.528 us; speedup 1.0000x reference)
//
#include <hip/hip_runtime.h>
#include <hip/hip_fp16.h>
#include <math.h>

#define NN 20000
#define NE 320000
#define H 256
#define LN_EPS 1e-5f
#define TE 64   // edges per block (edge kernel)

typedef _Float16 f16x8 __attribute__((ext_vector_type(8)));
typedef float f32x16 __attribute__((ext_vector_type(16)));

__device__ __forceinline__ float silu1(float v) {
    return __fdividef(v, 1.0f + __expf(-v));
}

__device__ __forceinline__ __half2 silu2(const __half2 s) {
    const __half2 one2 = __float2half2_rn(1.0f);
    return __hmul2(s, h2rcp(__hadd2(one2, h2exp(__hneg2(s)))));
}

// ---------------- misc kernel (NO pre zone — Bp1 consumer must be a
// separate launch: intra-kernel producer/consumer across blocks races) ------
// zones: [0,1250) hist, [1250,1485) xcopy, [1485,2125) pack, 2125 wdist,
//        [2126,3376) msg zero (consumer k_edge launches later — safe)
__global__ __launch_bounds__(256) void k_misc(
    const int* __restrict__ ei, int* __restrict__ bins,
    const float* __restrict__ x, float* __restrict__ xout,
    const float* __restrict__ ew2, const float* __restrict__ cw1,
    const float* __restrict__ nw2, const float* __restrict__ nw1,
    const float* __restrict__ ew1,
    _Float16* __restrict__ Bp2, _Float16* __restrict__ Bp3,
    _Float16* __restrict__ BpB, _Float16* __restrict__ BpA,
    _Float16* __restrict__ Bp1, _Float16* __restrict__ wdh,
    float* __restrict__ msg) {
    const int b = blockIdx.x;
    const int tid = threadIdx.x;
    if (b < 1250) {                           // hist
        atomicAdd(&bins[ei[NE + b * 256 + tid]], 1);
    } else if (b < 1485) {                    // xcopy
        const int i = (b - 1250) * 256 + tid;
        if (i < NN * 3) xout[i] = x[i];
    } else if (b < 2125) {                    // weight pack
        const int pb = b - 1485;
        const int which = pb >> 7;
        const int bx = pb & 127;
        const int n = tid;
        if (which < 3) {                      // K=256, N=256
            if (bx >= 64) return;
            const float* W = (which == 0) ? ew2 : (which == 1) ? cw1 : nw2;
            _Float16* Bp = (which == 0) ? Bp2 : (which == 1) ? Bp3 : BpB;
            #pragma unroll
            for (int kr = 0; kr < 4; kr++) {
                const int k = bx * 4 + kr;
                Bp[((size_t)(k >> 3) * 256 + n) * 8 + (k & 7)] =
                    (_Float16)W[(size_t)k * 256 + n];
            }
        } else if (which == 3) {              // nw1: K=512, N=256
            #pragma unroll
            for (int kr = 0; kr < 4; kr++) {
                const int k = bx * 4 + kr;
                BpA[((size_t)(k >> 3) * 256 + n) * 8 + (k & 7)] =
                    (_Float16)nw1[(size_t)k * 256 + n];
            }
        } else {                              // ew1 combined: K=256, N=512
            if (bx >= 64) return;
            #pragma unroll
            for (int kr = 0; kr < 4; kr++) {
                const int k = bx * 4 + kr;
                Bp1[((size_t)(k >> 3) * 512 + n) * 8 + (k & 7)] =
                    (_Float16)ew1[(size_t)k * 256 + n];
                Bp1[((size_t)(k >> 3) * 512 + 256 + n) * 8 + (k & 7)] =
                    (_Float16)ew1[(size_t)(256 + k) * 256 + n];
            }
        }
    } else if (b == 2125) {                   // wdist row of ew1 -> f16
        wdh[tid] = (_Float16)ew1[(size_t)512 * H + tid];
    } else {                                  // msg zero: 1250 blocks x 4 KB
        const int b2 = b - 2126;
        float4* m4 = (float4*)msg;
        const float4 z = make_float4(0.f, 0.f, 0.f, 0.f);
        #pragma unroll
        for (int k = 0; k < 4; k++)
            m4[(size_t)b2 * 256 + tid + (size_t)k * 320000] = z;
    }
}

// ---------------- pre (MFMA): [P|Q] = h @ [W_top|W_bot] (+b1 on P) ----------
// MUST launch after k_misc (consumes Bp1).
__global__ __launch_bounds__(256, 4) void k_pre(const float* __restrict__ h,
                                                const _Float16* __restrict__ Bp1,
                                                const float* __restrict__ eb1,
                                                _Float16* __restrict__ P,
                                                _Float16* __restrict__ Q) {
    __shared__ f16x8 Ap[32 * 32];
    const int tid = threadIdx.x;
    const int l = tid & 63;
    const int w = tid >> 6;
    const int l31 = l & 31;
    const int hh = l >> 5;
    const int n0 = blockIdx.x * 32;

    {
        const int kb = tid & 31;
        const int eb = tid >> 5;
        #pragma unroll
        for (int i = 0; i < 4; i++) {
            const int e = eb + i * 8;
            const float4 v0 = *(const float4*)(h + (size_t)(n0 + e) * H + kb * 8);
            const float4 v1 = *(const float4*)(h + (size_t)(n0 + e) * H + kb * 8 + 4);
            f16x8 pk;
            pk[0] = (_Float16)v0.x; pk[1] = (_Float16)v0.y;
            pk[2] = (_Float16)v0.z; pk[3] = (_Float16)v0.w;
            pk[4] = (_Float16)v1.x; pk[5] = (_Float16)v1.y;
            pk[6] = (_Float16)v1.z; pk[7] = (_Float16)v1.w;
            Ap[kb * 32 + (e ^ (kb & 7))] = pk;
        }
    }
    __syncthreads();

    const f16x8* Bv = (const f16x8*)Bp1;
    f32x16 acc[4];
    #pragma unroll
    for (int nt = 0; nt < 4; nt++)
        #pragma unroll
        for (int r = 0; r < 16; r++) acc[nt][r] = 0.0f;

    #pragma unroll 4
    for (int kk = 0; kk < 16; kk++) {
        const int kb = kk * 2 + hh;
        const f16x8 a = Ap[kb * 32 + (l31 ^ (kb & 7))];
        #pragma unroll
        for (int nt = 0; nt < 4; nt++) {
            const f16x8 bfr = Bv[(size_t)kb * 512 + w * 128 + nt * 32 + l31];
            acc[nt] = __builtin_amdgcn_mfma_f32_32x32x16_f16(a, bfr, acc[nt], 0, 0, 0);
        }
    }

    #pragma unroll
    for (int nt = 0; nt < 4; nt++) {
        const int col = w * 128 + nt * 32 + l31;
        const float bias = (col < 256) ? eb1[col] : 0.0f;
        #pragma unroll
        for (int r = 0; r < 16; r++) {
            const int node = n0 + (r & 3) + 8 * (r >> 2) + 4 * hh;
            const float v = acc[nt][r] + bias;
            if (col < 256) P[(size_t)node * H + col] = (_Float16)v;
            else           Q[(size_t)node * H + col - 256] = (_Float16)v;
        }
    }
}

// shuffle-based exclusive scan of 20000 bins, one block of 1024 threads
__global__ __launch_bounds__(1024) void k_scan(const int* __restrict__ bins,
                                               int* __restrict__ cursor) {
    __shared__ int wsum[16];
    __shared__ int wbase[16];
    const int tid = threadIdx.x;
    const int lane = tid & 63;
    const int wid = tid >> 6;
    const int base = tid * 20;
    int loc[20];
    int sum = 0;
    #pragma unroll
    for (int j = 0; j < 20; j++) {
        const int idx = base + j;
        const int v = (idx < NN) ? bins[idx] : 0;
        loc[j] = sum;
        sum += v;
    }
    int inc = sum;
    #pragma unroll
    for (int off = 1; off < 64; off <<= 1) {
        const int t = __shfl_up(inc, off);
        if (lane >= off) inc += t;
    }
    if (lane == 63) wsum[wid] = inc;
    __syncthreads();
    if (tid < 64) {
        int v = (tid < 16) ? wsum[tid] : 0;
        int inc2 = v;
        #pragma unroll
        for (int off = 1; off < 16; off <<= 1) {
            const int t = __shfl_up(inc2, off);
            if (lane >= off) inc2 += t;
        }
        if (tid < 16) wbase[tid] = inc2 - v;
    }
    __syncthreads();
    const int excl = wbase[wid] + inc - sum;
    #pragma unroll
    for (int j = 0; j < 20; j++) {
        const int idx = base + j;
        if (idx < NN) cursor[idx] = excl + loc[j];
    }
}

__global__ void k_scatter(const int* __restrict__ ei, int* __restrict__ cursor,
                          int* __restrict__ perm) {
    const int e = blockIdx.x * blockDim.x + threadIdx.x;
    if (e < NE) {
        const int c = ei[NE + e];
        const int pos = atomicAdd(&cursor[c], 1);
        perm[pos] = e;
    }
}

// ---------------- edge kernel: 64 edges/block, 256 threads, 4 waves ---------
// Wave w: M=64 (edges, two 32-row tiles a0/a1) x N=64 (channels w*64..+63).
__global__ __launch_bounds__(256, 4) void k_edge(
    const float* __restrict__ x, const int* __restrict__ ei,
    const int* __restrict__ perm,
    const _Float16* __restrict__ P, const _Float16* __restrict__ Q,
    const _Float16* __restrict__ wdh,
    const _Float16* __restrict__ Bp2, const float* __restrict__ eb2,
    const _Float16* __restrict__ Bp3, const float* __restrict__ cb1,
    const float* __restrict__ cw2,
    float* __restrict__ msg, float* __restrict__ xout) {
    __shared__ f16x8 Ap[32 * 64];     // 32 KB: m, then m_ij (A-frag layout)
    __shared__ float sdiff[TE][4];
    __shared__ int srow[TE];
    __shared__ int scol[TE];
    __shared__ float scw[TE];

    const int tid = threadIdx.x;      // 0..255
    const int e0blk = blockIdx.x * TE;
    const int l = tid & 63;
    const int w = tid >> 6;           // channel quarter: w*64
    const int l31 = l & 31;
    const int hh = l >> 5;

    if (tid < TE) {
        const int e = perm[e0blk + tid];
        const int r = ei[e];
        const int c = ei[NE + e];
        const float dx = x[r * 3 + 0] - x[c * 3 + 0];
        const float dy = x[r * 3 + 1] - x[c * 3 + 1];
        const float dz = x[r * 3 + 2] - x[c * 3 + 2];
        srow[tid] = r; scol[tid] = c;
        sdiff[tid][0] = dx; sdiff[tid][1] = dy; sdiff[tid][2] = dz;
        sdiff[tid][3] = dx * dx + dy * dy + dz * dz;
        scw[tid] = 0.0f;
    }
    __syncthreads();

    // ---- stage m = silu(P[row]+Q[col]+dsq*wd), packed f16 math ----
    {
        const f16x8* Pv = (const f16x8*)P;
        const f16x8* Qv = (const f16x8*)Q;
        const int kb = tid & 31;
        const int eb = tid >> 5;      // 0..7
        union { f16x8 v; __half2 h[4]; } wdu;
        wdu.v = ((const f16x8*)wdh)[kb];
        #pragma unroll 4
        for (int i = 0; i < 8; i++) {
            const int e = eb + i * 8;
            const __half2 d2 = __float2half2_rn(sdiff[e][3]);
            union { f16x8 v; __half2 h[4]; } pu, qu, su;
            pu.v = Pv[(size_t)srow[e] * 32 + kb];
            qu.v = Qv[(size_t)scol[e] * 32 + kb];
            #pragma unroll
            for (int j = 0; j < 4; j++) {
                const __half2 s = __hfma2(wdu.h[j], d2, __hadd2(pu.h[j], qu.h[j]));
                su.h[j] = silu2(s);
            }
            Ap[kb * 64 + (e ^ (kb & 7))] = su.v;
        }
    }
    __syncthreads();

    const f16x8* Bp2v = (const f16x8*)Bp2;
    const f16x8* Bp3v = (const f16x8*)Bp3;

    // ---- GEMM2: m_ij = silu(m @ e_w2 + e_b2), M=64 x N=64 per wave ----
    f32x16 acc0[2], acc1[2];
    #pragma unroll
    for (int nt = 0; nt < 2; nt++)
        #pragma unroll
        for (int r = 0; r < 16; r++) { acc0[nt][r] = 0.0f; acc1[nt][r] = 0.0f; }

    #pragma unroll 4
    for (int kk = 0; kk < 16; kk++) {
        const int kb = kk * 2 + hh;
        const f16x8 a0 = Ap[kb * 64 + (l31 ^ (kb & 7))];
        const f16x8 a1 = Ap[kb * 64 + ((32 + l31) ^ (kb & 7))];
        #pragma unroll
        for (int nt = 0; nt < 2; nt++) {
            const f16x8 b = Bp2v[(size_t)kb * 256 + w * 64 + nt * 32 + l31];
            acc0[nt] = __builtin_amdgcn_mfma_f32_32x32x16_f16(a0, b, acc0[nt], 0, 0, 0);
            acc1[nt] = __builtin_amdgcn_mfma_f32_32x32x16_f16(a1, b, acc1[nt], 0, 0, 0);
        }
    }

    __syncthreads();   // all waves done reading m from Ap

    // silu + bias (packed), write m_ij into Ap (A-frag layout)
    {
        __half* Aph = (__half*)Ap;
        #pragma unroll
        for (int nt = 0; nt < 2; nt++) {
            const int c = w * 64 + nt * 32 + l31;
            const float bias = eb2[c];
            const int kb2 = c >> 3;
            const int j = c & 7;
            #pragma unroll
            for (int r = 0; r < 16; r++) {
                const __half2 o = silu2(__floats2half2_rn(acc0[nt][r] + bias,
                                                          acc1[nt][r] + bias));
                const int e0 = (r & 3) + 8 * (r >> 2) + 4 * hh;
                Aph[(size_t)(kb2 * 64 + (e0 ^ (kb2 & 7))) * 8 + j] = __low2half(o);
                Aph[(size_t)(kb2 * 64 + ((e0 + 32) ^ (kb2 & 7))) * 8 + j] = __high2half(o);
            }
        }
    }
    __syncthreads();

    // ---- GEMM3: p = m_ij @ c_w1 + c_b1; cw = silu(p) . c_w2 ----
    #pragma unroll
    for (int nt = 0; nt < 2; nt++)
        #pragma unroll
        for (int r = 0; r < 16; r++) { acc0[nt][r] = 0.0f; acc1[nt][r] = 0.0f; }

    #pragma unroll 4
    for (int kk = 0; kk < 16; kk++) {
        const int kb = kk * 2 + hh;
        const f16x8 a0 = Ap[kb * 64 + (l31 ^ (kb & 7))];
        const f16x8 a1 = Ap[kb * 64 + ((32 + l31) ^ (kb & 7))];
        #pragma unroll
        for (int nt = 0; nt < 2; nt++) {
            const f16x8 b = Bp3v[(size_t)kb * 256 + w * 64 + nt * 32 + l31];
            acc0[nt] = __builtin_amdgcn_mfma_f32_32x32x16_f16(a0, b, acc0[nt], 0, 0, 0);
            acc1[nt] = __builtin_amdgcn_mfma_f32_32x32x16_f16(a1, b, acc1[nt], 0, 0, 0);
        }
    }

    {
        __half2 p[16];
        #pragma unroll
        for (int r = 0; r < 16; r++) p[r] = __float2half2_rn(0.0f);
        #pragma unroll
        for (int nt = 0; nt < 2; nt++) {
            const int c = w * 64 + nt * 32 + l31;
            const float bias = cb1[c];
            const __half2 cwv = __float2half2_rn(cw2[c]);
            #pragma unroll
            for (int r = 0; r < 16; r++) {
                const __half2 s = __floats2half2_rn(acc0[nt][r] + bias,
                                                    acc1[nt][r] + bias);
                p[r] = __hfma2(silu2(s), cwv, p[r]);
            }
        }
        #pragma unroll
        for (int m = 1; m < 32; m <<= 1) {
            #pragma unroll
            for (int r = 0; r < 16; r++) {
                union { __half2 h; int i; } u, v;
                u.h = p[r];
                v.i = __shfl_xor(u.i, m);
                p[r] = __hadd2(u.h, v.h);
            }
        }
        if (l31 == 0) {
            #pragma unroll
            for (int r = 0; r < 16; r++) {
                const int e0 = (r & 3) + 8 * (r >> 2) + 4 * hh;
                atomicAdd(&scw[e0], __low2float(p[r]));
                atomicAdd(&scw[e0 + 32], __high2float(p[r]));
            }
        }
    }
    __syncthreads();   // scw + m_ij complete

    // ---- msg segmented reduction: 2 groups of 128 threads; group g walks
    // edges [g*32, g*32+32), thread owns a channel PAIR (half2 reads/adds).
    // Each group still flushes the FULL 256-channel row at one trip point
    // (time-coherent -> L2 merges into full-line writes; round-11 lesson).
    {
        const __half* Aph = (const __half*)Ap;
        const int half = tid >> 7;            // wave-uniform
        const int tloc = tid & 127;
        const int kb = tloc >> 2;
        const int j2 = tloc & 3;              // halfword pair j = 2*j2
        const int c0 = kb * 8 + j2 * 2;
        const int eend = half * 32 + 32;
        __half2 acc = __float2half2_rn(0.0f);
        #pragma unroll 4
        for (int e = half * 32; e < eend; e++) {
            const __half2 m2 = *(const __half2*)
                (Aph + (size_t)(kb * 64 + (e ^ (kb & 7))) * 8 + j2 * 2);
            acc = __hadd2(acc, m2);
            const int col = scol[e];
            const bool flush = (e == eend - 1) || (col != scol[e + 1]);
            if (flush) {
                float* dst = msg + (size_t)col * H + c0;
                atomicAdd(dst + 0, __low2float(acc));
                atomicAdd(dst + 1, __high2float(acc));
                acc = __float2half2_rn(0.0f);
            }
        }
    }

    // ---- coord segmented reduction ----
    if (tid < 3) {
        const int d = tid;
        float accc = 0.0f;
        for (int e = 0; e < TE; e++) {
            accc += scw[e] * sdiff[e][d];
            const int col = scol[e];
            const int nxt = (e == TE - 1) ? -1 : scol[e + 1];
            if (col != nxt) {
                atomicAdd(xout + (size_t)col * 3 + d, accc);
                accc = 0.0f;
            }
        }
    }
}

// ---------------- node kernel (MFMA): 32 nodes/block, 256 threads -----------
// Tp aliases ApA's storage (ApA fully consumed by GEMM A) -> 33 KB LDS,
// 4 blocks/CU.
__global__ __launch_bounds__(256, 4) void k_node(
    const float* __restrict__ h, const float* __restrict__ msg,
    const _Float16* __restrict__ BpA, const float* __restrict__ nb1,
    const _Float16* __restrict__ BpB, const float* __restrict__ nb2,
    const float* __restrict__ lng, const float* __restrict__ lnb,
    float* __restrict__ hout) {
    __shared__ f16x8 ApA[64 * 32];
    __shared__ float s1[32];
    __shared__ float s2[32];
    f16x8* Tp = ApA;   // reused after GEMM A (guarded by syncthreads)
    const int tid = threadIdx.x;
    const int l = tid & 63;
    const int w = tid >> 6;
    const int l31 = l & 31;
    const int hh = l >> 5;
    const int n0 = blockIdx.x * 32;

    if (tid < 32) { s1[tid] = 0.0f; s2[tid] = 0.0f; }

    {
        const int kb = tid & 31;
        const int eb = tid >> 5;
        #pragma unroll
        for (int i = 0; i < 4; i++) {
            const int e = eb + i * 8;
            #pragma unroll
            for (int half = 0; half < 2; half++) {
                const float* A = half ? msg : h;
                const int kb2 = kb + half * 32;
                const float4 v0 = *(const float4*)(A + (size_t)(n0 + e) * H + kb * 8);
                const float4 v1 = *(const float4*)(A + (size_t)(n0 + e) * H + kb * 8 + 4);
                f16x8 pk;
                pk[0] = (_Float16)v0.x; pk[1] = (_Float16)v0.y;
                pk[2] = (_Float16)v0.z; pk[3] = (_Float16)v0.w;
                pk[4] = (_Float16)v1.x; pk[5] = (_Float16)v1.y;
                pk[6] = (_Float16)v1.z; pk[7] = (_Float16)v1.w;
                ApA[kb2 * 32 + (e ^ (kb2 & 7))] = pk;
            }
        }
    }
    __syncthreads();

    const f16x8* BvA = (const f16x8*)BpA;
    const f16x8* BvB = (const f16x8*)BpB;

    f32x16 acc[2];
    #pragma unroll
    for (int nt = 0; nt < 2; nt++)
        #pragma unroll
        for (int r = 0; r < 16; r++) acc[nt][r] = 0.0f;

    #pragma unroll 4
    for (int kk = 0; kk < 32; kk++) {
        const int kb = kk * 2 + hh;
        const f16x8 a = ApA[kb * 32 + (l31 ^ (kb & 7))];
        #pragma unroll
        for (int nt = 0; nt < 2; nt++) {
            const f16x8 b = BvA[(size_t)kb * 256 + w * 64 + nt * 32 + l31];
            acc[nt] = __builtin_amdgcn_mfma_f32_32x32x16_f16(a, b, acc[nt], 0, 0, 0);
        }
    }
    __syncthreads();   // everyone done reading ApA before Tp overwrites it

    {
        _Float16* Tpf = (_Float16*)Tp;
        #pragma unroll
        for (int nt = 0; nt < 2; nt++) {
            const int col = w * 64 + nt * 32 + l31;
            const float bias = nb1[col];
            const int kb2 = col >> 3;
            const int j = col & 7;
            #pragma unroll
            for (int r = 0; r < 16; r++) {
                const int e = (r & 3) + 8 * (r >> 2) + 4 * hh;
                Tpf[(size_t)(kb2 * 32 + (e ^ (kb2 & 7))) * 8 + j] =
                    (_Float16)silu1(acc[nt][r] + bias);
            }
        }
    }
    __syncthreads();

    f32x16 y[2];
    #pragma unroll
    for (int nt = 0; nt < 2; nt++)
        #pragma unroll
        for (int r = 0; r < 16; r++) y[nt][r] = 0.0f;

    #pragma unroll 4
    for (int kk = 0; kk < 16; kk++) {
        const int kb = kk * 2 + hh;
        const f16x8 a = Tp[kb * 32 + (l31 ^ (kb & 7))];
        #pragma unroll
        for (int nt = 0; nt < 2; nt++) {
            const f16x8 b = BvB[(size_t)kb * 256 + w * 64 + nt * 32 + l31];
            y[nt] = __builtin_amdgcn_mfma_f32_32x32x16_f16(a, b, y[nt], 0, 0, 0);
        }
    }

    float t1[16], t2[16];
    #pragma unroll
    for (int r = 0; r < 16; r++) { t1[r] = 0.0f; t2[r] = 0.0f; }
    #pragma unroll
    for (int nt = 0; nt < 2; nt++) {
        const int col = w * 64 + nt * 32 + l31;
        const float bias = nb2[col];
        #pragma unroll
        for (int r = 0; r < 16; r++) {
            const int node = n0 + (r & 3) + 8 * (r >> 2) + 4 * hh;
            const float v = y[nt][r] + bias + h[(size_t)node * H + col];
            y[nt][r] = v;
            t1[r] += v;
            t2[r] += v * v;
        }
    }
    #pragma unroll
    for (int m = 1; m < 32; m <<= 1) {
        #pragma unroll
        for (int r = 0; r < 16; r++) {
            t1[r] += __shfl_xor(t1[r], m);
            t2[r] += __shfl_xor(t2[r], m);
        }
    }
    if (l31 == 0) {
        #pragma unroll
        for (int r = 0; r < 16; r++) {
            const int row = (r & 3) + 8 * (r >> 2) + 4 * hh;
            atomicAdd(&s1[row], t1[r]);
            atomicAdd(&s2[row], t2[r]);
        }
    }
    __syncthreads();

    #pragma unroll
    for (int nt = 0; nt < 2; nt++) {
        const int col = w * 64 + nt * 32 + l31;
        const float g = lng[col];
        const float bb = lnb[col];
        #pragma unroll
        for (int r = 0; r < 16; r++) {
            const int row = (r & 3) + 8 * (r >> 2) + 4 * hh;
            const int node = n0 + row;
            const float mu = s1[row] * (1.0f / H);
            const float var = s2[row] * (1.0f / H) - mu * mu;
            const float rs = rsqrtf(var + LN_EPS);
            hout[(size_t)node * H + col] = (y[nt][r] - mu) * rs * g + bb;
        }
    }
}

extern "C" void kernel_launch(void* const* d_in, const int* in_sizes, int n_in,
                              void* d_out, int out_size, void* d_ws, size_t ws_size,
                              hipStream_t stream) {
    const float* h   = (const float*)d_in[0];
    const float* x   = (const float*)d_in[1];
    const int*   ei  = (const int*)d_in[2];
    const float* ew1 = (const float*)d_in[3];
    const float* eb1 = (const float*)d_in[4];
    const float* ew2 = (const float*)d_in[5];
    const float* eb2 = (const float*)d_in[6];
    const float* cw1 = (const float*)d_in[7];
    const float* cb1 = (const float*)d_in[8];
    const float* cw2 = (const float*)d_in[9];
    const float* nw1 = (const float*)d_in[10];
    const float* nb1 = (const float*)d_in[11];
    const float* nw2 = (const float*)d_in[12];
    const float* nb2 = (const float*)d_in[13];
    const float* lng = (const float*)d_in[14];
    const float* lnb = (const float*)d_in[15];

    float* hout = (float*)d_out;
    float* xout = hout + (size_t)NN * H;

    float* msg = (float*)d_ws;                              // NN*H f32
    int* bins = (int*)(msg + (size_t)NN * H);               // NN (memset)
    _Float16* P   = (_Float16*)(bins + NN);                 // NN*H f16
    _Float16* Qq  = P + (size_t)NN * H;                     // NN*H f16
    _Float16* Bp2 = Qq + (size_t)NN * H;                    // 256*256
    _Float16* Bp3 = Bp2 + 256 * 256;
    _Float16* BpB = Bp3 + 256 * 256;
    _Float16* BpA = BpB + 256 * 256;                        // 512*256
    _Float16* Bp1 = BpA + 512 * 256;                        // 256*512
    _Float16* wdh = Bp1 + 256 * 512;                        // 256
    int* cursor = (int*)(wdh + 256);
    int* perm   = cursor + NN;

    (void)hipMemsetAsync(bins, 0, (size_t)NN * 4, stream);
    k_misc<<<3376, 256, 0, stream>>>(ei, bins, x, xout, ew2, cw1, nw2, nw1, ew1,
                                     Bp2, Bp3, BpB, BpA, Bp1, wdh, msg);
    k_pre<<<NN / 32, 256, 0, stream>>>(h, Bp1, eb1, P, Qq);
    k_scan<<<1, 1024, 0, stream>>>(bins, cursor);
    k_scatter<<<(NE + 255) / 256, 256, 0, stream>>>(ei, cursor, perm);
    k_edge<<<NE / TE, 256, 0, stream>>>(x, ei, perm, P, Qq, wdh, Bp2, eb2,
                                        Bp3, cb1, cw2, msg, xout);
    k_node<<<NN / 32, 256, 0, stream>>>(h, msg, BpA, nb1, BpB, nb2,
                                        lng, lnb, hout);
}

// Round 14
// 360.507 us; speedup vs baseline: 1.0167x; 1.0167x over previous
//
#include <hip/hip_runtime.h>
#include <hip/hip_fp16.h>
#include <math.h>

#define NN 20000
#define NE 320000
#define H 256
#define LN_EPS 1e-5f
#define TE 64   // edges per block (edge kernel)

typedef _Float16 f16x8 __attribute__((ext_vector_type(8)));
typedef float f32x16 __attribute__((ext_vector_type(16)));

__device__ __forceinline__ float silu1(float v) {
    return __fdividef(v, 1.0f + __expf(-v));
}

__device__ __forceinline__ __half2 silu2(const __half2 s) {
    const __half2 one2 = __float2half2_rn(1.0f);
    return __hmul2(s, h2rcp(__hadd2(one2, h2exp(__hneg2(s)))));
}

// ---------------- misc kernel (NO consumer of same-launch data!) ----------
// zones: [0,1250) hist, [1250,1485) xcopy, [1485,2125) pack, 2125 wdist,
//        [2126,3376) msg zero (consumer k_edge launches later — safe)
__global__ __launch_bounds__(256) void k_misc(
    const int* __restrict__ ei, int* __restrict__ bins,
    const float* __restrict__ x, float* __restrict__ xout,
    const float* __restrict__ ew2, const float* __restrict__ cw1,
    const float* __restrict__ nw2, const float* __restrict__ nw1,
    const float* __restrict__ ew1,
    _Float16* __restrict__ Bp2, _Float16* __restrict__ Bp3,
    _Float16* __restrict__ BpB, _Float16* __restrict__ BpA,
    _Float16* __restrict__ Bp1, _Float16* __restrict__ wdh,
    float* __restrict__ msg) {
    const int b = blockIdx.x;
    const int tid = threadIdx.x;
    if (b < 1250) {                           // hist
        atomicAdd(&bins[ei[NE + b * 256 + tid]], 1);
    } else if (b < 1485) {                    // xcopy
        const int i = (b - 1250) * 256 + tid;
        if (i < NN * 3) xout[i] = x[i];
    } else if (b < 2125) {                    // weight pack
        const int pb = b - 1485;
        const int which = pb >> 7;
        const int bx = pb & 127;
        const int n = tid;
        if (which < 3) {                      // K=256, N=256
            if (bx >= 64) return;
            const float* W = (which == 0) ? ew2 : (which == 1) ? cw1 : nw2;
            _Float16* Bp = (which == 0) ? Bp2 : (which == 1) ? Bp3 : BpB;
            #pragma unroll
            for (int kr = 0; kr < 4; kr++) {
                const int k = bx * 4 + kr;
                Bp[((size_t)(k >> 3) * 256 + n) * 8 + (k & 7)] =
                    (_Float16)W[(size_t)k * 256 + n];
            }
        } else if (which == 3) {              // nw1: K=512, N=256
            #pragma unroll
            for (int kr = 0; kr < 4; kr++) {
                const int k = bx * 4 + kr;
                BpA[((size_t)(k >> 3) * 256 + n) * 8 + (k & 7)] =
                    (_Float16)nw1[(size_t)k * 256 + n];
            }
        } else {                              // ew1 combined: K=256, N=512
            if (bx >= 64) return;
            #pragma unroll
            for (int kr = 0; kr < 4; kr++) {
                const int k = bx * 4 + kr;
                Bp1[((size_t)(k >> 3) * 512 + n) * 8 + (k & 7)] =
                    (_Float16)ew1[(size_t)k * 256 + n];
                Bp1[((size_t)(k >> 3) * 512 + 256 + n) * 8 + (k & 7)] =
                    (_Float16)ew1[(size_t)(256 + k) * 256 + n];
            }
        }
    } else if (b == 2125) {                   // wdist row of ew1 -> f16
        wdh[tid] = (_Float16)ew1[(size_t)512 * H + tid];
    } else {                                  // msg zero: 1250 blocks x 4 KB
        const int b2 = b - 2126;
        float4* m4 = (float4*)msg;
        const float4 z = make_float4(0.f, 0.f, 0.f, 0.f);
        #pragma unroll
        for (int k = 0; k < 4; k++)
            m4[(size_t)b2 * 256 + tid + (size_t)k * 320000] = z;
    }
}

// ---------------- pre (MFMA) + scan tail block ------------------------------
// blocks [0,625): [P|Q] = h @ [W_top|W_bot] (+b1 on P), f16 out.
// block 625: exclusive scan of bins -> cursor (consumes k_misc's bins;
// separate launch from k_misc so the dependency is safe).
__global__ __launch_bounds__(256, 4) void k_pre(const float* __restrict__ h,
                                                const _Float16* __restrict__ Bp1,
                                                const float* __restrict__ eb1,
                                                _Float16* __restrict__ P,
                                                _Float16* __restrict__ Q,
                                                const int* __restrict__ bins,
                                                int* __restrict__ cursor) {
    __shared__ f16x8 Ap[32 * 32];
    const int tid = threadIdx.x;

    if (blockIdx.x == NN / 32) {              // ---- scan zone ----
        __shared__ int wsum2[4];
        __shared__ int wbase2[4];
        const int lane = tid & 63;
        const int wid = tid >> 6;
        const int base = tid * 79;            // 256*79 = 20224 >= 20000
        int sum = 0;
        for (int j = 0; j < 79; j++) {
            const int idx = base + j;
            sum += (idx < NN) ? bins[idx] : 0;
        }
        int inc = sum;
        #pragma unroll
        for (int off = 1; off < 64; off <<= 1) {
            const int t = __shfl_up(inc, off);
            if (lane >= off) inc += t;
        }
        if (lane == 63) wsum2[wid] = inc;
        __syncthreads();
        if (tid == 0) {
            int r = 0;
            #pragma unroll
            for (int ww = 0; ww < 4; ww++) { wbase2[ww] = r; r += wsum2[ww]; }
        }
        __syncthreads();
        int run = wbase2[wid] + inc - sum;    // exclusive prefix
        for (int j = 0; j < 79; j++) {
            const int idx = base + j;
            if (idx < NN) { const int v = bins[idx]; cursor[idx] = run; run += v; }
        }
        return;
    }

    const int l = tid & 63;
    const int w = tid >> 6;
    const int l31 = l & 31;
    const int hh = l >> 5;
    const int n0 = blockIdx.x * 32;

    {
        const int kb = tid & 31;
        const int eb = tid >> 5;
        #pragma unroll
        for (int i = 0; i < 4; i++) {
            const int e = eb + i * 8;
            const float4 v0 = *(const float4*)(h + (size_t)(n0 + e) * H + kb * 8);
            const float4 v1 = *(const float4*)(h + (size_t)(n0 + e) * H + kb * 8 + 4);
            f16x8 pk;
            pk[0] = (_Float16)v0.x; pk[1] = (_Float16)v0.y;
            pk[2] = (_Float16)v0.z; pk[3] = (_Float16)v0.w;
            pk[4] = (_Float16)v1.x; pk[5] = (_Float16)v1.y;
            pk[6] = (_Float16)v1.z; pk[7] = (_Float16)v1.w;
            Ap[kb * 32 + (e ^ (kb & 7))] = pk;
        }
    }
    __syncthreads();

    const f16x8* Bv = (const f16x8*)Bp1;
    f32x16 acc[4];
    #pragma unroll
    for (int nt = 0; nt < 4; nt++)
        #pragma unroll
        for (int r = 0; r < 16; r++) acc[nt][r] = 0.0f;

    #pragma unroll 4
    for (int kk = 0; kk < 16; kk++) {
        const int kb = kk * 2 + hh;
        const f16x8 a = Ap[kb * 32 + (l31 ^ (kb & 7))];
        #pragma unroll
        for (int nt = 0; nt < 4; nt++) {
            const f16x8 bfr = Bv[(size_t)kb * 512 + w * 128 + nt * 32 + l31];
            acc[nt] = __builtin_amdgcn_mfma_f32_32x32x16_f16(a, bfr, acc[nt], 0, 0, 0);
        }
    }

    #pragma unroll
    for (int nt = 0; nt < 4; nt++) {
        const int col = w * 128 + nt * 32 + l31;
        const float bias = (col < 256) ? eb1[col] : 0.0f;
        #pragma unroll
        for (int r = 0; r < 16; r++) {
            const int node = n0 + (r & 3) + 8 * (r >> 2) + 4 * hh;
            const float v = acc[nt][r] + bias;
            if (col < 256) P[(size_t)node * H + col] = (_Float16)v;
            else           Q[(size_t)node * H + col - 256] = (_Float16)v;
        }
    }
}

__global__ void k_scatter(const int* __restrict__ ei, int* __restrict__ cursor,
                          int* __restrict__ perm) {
    const int e = blockIdx.x * blockDim.x + threadIdx.x;
    if (e < NE) {
        const int c = ei[NE + e];
        const int pos = atomicAdd(&cursor[c], 1);
        perm[pos] = e;
    }
}

// ---------------- edge kernel: 64 edges/block, 256 threads, 4 waves ---------
// Wave w: M=64 (edges, two 32-row tiles a0/a1) x N=64 (channels w*64..+63).
__global__ __launch_bounds__(256, 4) void k_edge(
    const float* __restrict__ x, const int* __restrict__ ei,
    const int* __restrict__ perm,
    const _Float16* __restrict__ P, const _Float16* __restrict__ Q,
    const _Float16* __restrict__ wdh,
    const _Float16* __restrict__ Bp2, const float* __restrict__ eb2,
    const _Float16* __restrict__ Bp3, const float* __restrict__ cb1,
    const float* __restrict__ cw2,
    float* __restrict__ msg, float* __restrict__ xout) {
    __shared__ f16x8 Ap[32 * 64];     // 32 KB: m, then m_ij (A-frag layout)
    __shared__ float sdiff[TE][4];
    __shared__ int srow[TE];
    __shared__ int scol[TE];
    __shared__ float scw[TE];

    const int tid = threadIdx.x;      // 0..255
    const int e0blk = blockIdx.x * TE;
    const int l = tid & 63;
    const int w = tid >> 6;           // channel quarter: w*64
    const int l31 = l & 31;
    const int hh = l >> 5;

    if (tid < TE) {
        const int e = perm[e0blk + tid];
        const int r = ei[e];
        const int c = ei[NE + e];
        const float dx = x[r * 3 + 0] - x[c * 3 + 0];
        const float dy = x[r * 3 + 1] - x[c * 3 + 1];
        const float dz = x[r * 3 + 2] - x[c * 3 + 2];
        srow[tid] = r; scol[tid] = c;
        sdiff[tid][0] = dx; sdiff[tid][1] = dy; sdiff[tid][2] = dz;
        sdiff[tid][3] = dx * dx + dy * dy + dz * dz;
        scw[tid] = 0.0f;
    }
    __syncthreads();

    // flush bitmask: bit e set iff e ends a col-run (wave-uniform via ballot)
    const unsigned long long fmask =
        __ballot((l == 63) || (scol[l] != scol[l + 1]));

    // ---- stage m = silu(P[row]+Q[col]+dsq*wd), packed f16 math ----
    {
        const f16x8* Pv = (const f16x8*)P;
        const f16x8* Qv = (const f16x8*)Q;
        const int kb = tid & 31;
        const int eb = tid >> 5;      // 0..7
        union { f16x8 v; __half2 h[4]; } wdu;
        wdu.v = ((const f16x8*)wdh)[kb];
        #pragma unroll 4
        for (int i = 0; i < 8; i++) {
            const int e = eb + i * 8;
            const __half2 d2 = __float2half2_rn(sdiff[e][3]);
            union { f16x8 v; __half2 h[4]; } pu, qu, su;
            pu.v = Pv[(size_t)srow[e] * 32 + kb];
            qu.v = Qv[(size_t)scol[e] * 32 + kb];
            #pragma unroll
            for (int j = 0; j < 4; j++) {
                const __half2 s = __hfma2(wdu.h[j], d2, __hadd2(pu.h[j], qu.h[j]));
                su.h[j] = silu2(s);
            }
            Ap[kb * 64 + (e ^ (kb & 7))] = su.v;
        }
    }
    __syncthreads();

    const f16x8* Bp2v = (const f16x8*)Bp2;
    const f16x8* Bp3v = (const f16x8*)Bp3;

    // ---- GEMM2: m_ij = silu(m @ e_w2 + e_b2), M=64 x N=64 per wave ----
    f32x16 acc0[2], acc1[2];
    #pragma unroll
    for (int nt = 0; nt < 2; nt++)
        #pragma unroll
        for (int r = 0; r < 16; r++) { acc0[nt][r] = 0.0f; acc1[nt][r] = 0.0f; }

    #pragma unroll 4
    for (int kk = 0; kk < 16; kk++) {
        const int kb = kk * 2 + hh;
        const f16x8 a0 = Ap[kb * 64 + (l31 ^ (kb & 7))];
        const f16x8 a1 = Ap[kb * 64 + ((32 + l31) ^ (kb & 7))];
        #pragma unroll
        for (int nt = 0; nt < 2; nt++) {
            const f16x8 b = Bp2v[(size_t)kb * 256 + w * 64 + nt * 32 + l31];
            acc0[nt] = __builtin_amdgcn_mfma_f32_32x32x16_f16(a0, b, acc0[nt], 0, 0, 0);
            acc1[nt] = __builtin_amdgcn_mfma_f32_32x32x16_f16(a1, b, acc1[nt], 0, 0, 0);
        }
    }

    __syncthreads();   // all waves done reading m from Ap

    // silu + bias (packed), write m_ij into Ap (A-frag layout)
    {
        __half* Aph = (__half*)Ap;
        #pragma unroll
        for (int nt = 0; nt < 2; nt++) {
            const int c = w * 64 + nt * 32 + l31;
            const float bias = eb2[c];
            const int kb2 = c >> 3;
            const int j = c & 7;
            #pragma unroll
            for (int r = 0; r < 16; r++) {
                const __half2 o = silu2(__floats2half2_rn(acc0[nt][r] + bias,
                                                          acc1[nt][r] + bias));
                const int e0 = (r & 3) + 8 * (r >> 2) + 4 * hh;
                Aph[(size_t)(kb2 * 64 + (e0 ^ (kb2 & 7))) * 8 + j] = __low2half(o);
                Aph[(size_t)(kb2 * 64 + ((e0 + 32) ^ (kb2 & 7))) * 8 + j] = __high2half(o);
            }
        }
    }
    __syncthreads();

    // ---- GEMM3: p = m_ij @ c_w1 + c_b1; cw = silu(p) . c_w2 ----
    #pragma unroll
    for (int nt = 0; nt < 2; nt++)
        #pragma unroll
        for (int r = 0; r < 16; r++) { acc0[nt][r] = 0.0f; acc1[nt][r] = 0.0f; }

    #pragma unroll 4
    for (int kk = 0; kk < 16; kk++) {
        const int kb = kk * 2 + hh;
        const f16x8 a0 = Ap[kb * 64 + (l31 ^ (kb & 7))];
        const f16x8 a1 = Ap[kb * 64 + ((32 + l31) ^ (kb & 7))];
        #pragma unroll
        for (int nt = 0; nt < 2; nt++) {
            const f16x8 b = Bp3v[(size_t)kb * 256 + w * 64 + nt * 32 + l31];
            acc0[nt] = __builtin_amdgcn_mfma_f32_32x32x16_f16(a0, b, acc0[nt], 0, 0, 0);
            acc1[nt] = __builtin_amdgcn_mfma_f32_32x32x16_f16(a1, b, acc1[nt], 0, 0, 0);
        }
    }

    {
        __half2 p[16];
        #pragma unroll
        for (int r = 0; r < 16; r++) p[r] = __float2half2_rn(0.0f);
        #pragma unroll
        for (int nt = 0; nt < 2; nt++) {
            const int c = w * 64 + nt * 32 + l31;
            const float bias = cb1[c];
            const __half2 cwv = __float2half2_rn(cw2[c]);
            #pragma unroll
            for (int r = 0; r < 16; r++) {
                const __half2 s = __floats2half2_rn(acc0[nt][r] + bias,
                                                    acc1[nt][r] + bias);
                p[r] = __hfma2(silu2(s), cwv, p[r]);
            }
        }
        #pragma unroll
        for (int m = 1; m < 32; m <<= 1) {
            #pragma unroll
            for (int r = 0; r < 16; r++) {
                union { __half2 h; int i; } u, v;
                u.h = p[r];
                v.i = __shfl_xor(u.i, m);
                p[r] = __hadd2(u.h, v.h);
            }
        }
        if (l31 == 0) {
            #pragma unroll
            for (int r = 0; r < 16; r++) {
                const int e0 = (r & 3) + 8 * (r >> 2) + 4 * hh;
                atomicAdd(&scw[e0], __low2float(p[r]));
                atomicAdd(&scw[e0 + 32], __high2float(p[r]));
            }
        }
    }
    __syncthreads();   // scw + m_ij complete

    // ---- msg segmented reduction: thread owns channel tid (f32 atomics) ----
    // Channel-major walk: all 256 threads flush the SAME col at the same trip
    // point -> full 1 KB row written at once -> L2 merges into full-line HBM
    // writes (round-11 lesson: any split causes write amplification).
    // Flush points via precomputed wave-uniform bitmask (saves 2 LDS reads +
    // cmp per iteration).
    {
        const _Float16* Apf = (const _Float16*)Ap;
        const int c = tid;
        const int kb = c >> 3;
        const int j = c & 7;
        float accm = 0.0f;
        #pragma unroll 4
        for (int e = 0; e < TE; e++) {
            accm += (float)Apf[(size_t)(kb * 64 + (e ^ (kb & 7))) * 8 + j];
            if ((fmask >> e) & 1ull) {
                atomicAdd(msg + (size_t)scol[e] * H + c, accm);
                accm = 0.0f;
            }
        }
    }

    // ---- coord segmented reduction ----
    if (tid < 3) {
        const int d = tid;
        float accc = 0.0f;
        for (int e = 0; e < TE; e++) {
            accc += scw[e] * sdiff[e][d];
            if ((fmask >> e) & 1ull) {
                atomicAdd(xout + (size_t)scol[e] * 3 + d, accc);
                accc = 0.0f;
            }
        }
    }
}

// ---------------- node kernel (MFMA): 32 nodes/block, 256 threads -----------
// Tp aliases ApA's storage (ApA fully consumed by GEMM A) -> 33 KB LDS,
// 4 blocks/CU.
__global__ __launch_bounds__(256, 4) void k_node(
    const float* __restrict__ h, const float* __restrict__ msg,
    const _Float16* __restrict__ BpA, const float* __restrict__ nb1,
    const _Float16* __restrict__ BpB, const float* __restrict__ nb2,
    const float* __restrict__ lng, const float* __restrict__ lnb,
    float* __restrict__ hout) {
    __shared__ f16x8 ApA[64 * 32];
    __shared__ float s1[32];
    __shared__ float s2[32];
    f16x8* Tp = ApA;   // reused after GEMM A (guarded by syncthreads)
    const int tid = threadIdx.x;
    const int l = tid & 63;
    const int w = tid >> 6;
    const int l31 = l & 31;
    const int hh = l >> 5;
    const int n0 = blockIdx.x * 32;

    if (tid < 32) { s1[tid] = 0.0f; s2[tid] = 0.0f; }

    {
        const int kb = tid & 31;
        const int eb = tid >> 5;
        #pragma unroll
        for (int i = 0; i < 4; i++) {
            const int e = eb + i * 8;
            #pragma unroll
            for (int half = 0; half < 2; half++) {
                const float* A = half ? msg : h;
                const int kb2 = kb + half * 32;
                const float4 v0 = *(const float4*)(A + (size_t)(n0 + e) * H + kb * 8);
                const float4 v1 = *(const float4*)(A + (size_t)(n0 + e) * H + kb * 8 + 4);
                f16x8 pk;
                pk[0] = (_Float16)v0.x; pk[1] = (_Float16)v0.y;
                pk[2] = (_Float16)v0.z; pk[3] = (_Float16)v0.w;
                pk[4] = (_Float16)v1.x; pk[5] = (_Float16)v1.y;
                pk[6] = (_Float16)v1.z; pk[7] = (_Float16)v1.w;
                ApA[kb2 * 32 + (e ^ (kb2 & 7))] = pk;
            }
        }
    }
    __syncthreads();

    const f16x8* BvA = (const f16x8*)BpA;
    const f16x8* BvB = (const f16x8*)BpB;

    f32x16 acc[2];
    #pragma unroll
    for (int nt = 0; nt < 2; nt++)
        #pragma unroll
        for (int r = 0; r < 16; r++) acc[nt][r] = 0.0f;

    #pragma unroll 4
    for (int kk = 0; kk < 32; kk++) {
        const int kb = kk * 2 + hh;
        const f16x8 a = ApA[kb * 32 + (l31 ^ (kb & 7))];
        #pragma unroll
        for (int nt = 0; nt < 2; nt++) {
            const f16x8 b = BvA[(size_t)kb * 256 + w * 64 + nt * 32 + l31];
            acc[nt] = __builtin_amdgcn_mfma_f32_32x32x16_f16(a, b, acc[nt], 0, 0, 0);
        }
    }
    __syncthreads();   // everyone done reading ApA before Tp overwrites it

    {
        _Float16* Tpf = (_Float16*)Tp;
        #pragma unroll
        for (int nt = 0; nt < 2; nt++) {
            const int col = w * 64 + nt * 32 + l31;
            const float bias = nb1[col];
            const int kb2 = col >> 3;
            const int j = col & 7;
            #pragma unroll
            for (int r = 0; r < 16; r++) {
                const int e = (r & 3) + 8 * (r >> 2) + 4 * hh;
                Tpf[(size_t)(kb2 * 32 + (e ^ (kb2 & 7))) * 8 + j] =
                    (_Float16)silu1(acc[nt][r] + bias);
            }
        }
    }
    __syncthreads();

    f32x16 y[2];
    #pragma unroll
    for (int nt = 0; nt < 2; nt++)
        #pragma unroll
        for (int r = 0; r < 16; r++) y[nt][r] = 0.0f;

    #pragma unroll 4
    for (int kk = 0; kk < 16; kk++) {
        const int kb = kk * 2 + hh;
        const f16x8 a = Tp[kb * 32 + (l31 ^ (kb & 7))];
        #pragma unroll
        for (int nt = 0; nt < 2; nt++) {
            const f16x8 b = BvB[(size_t)kb * 256 + w * 64 + nt * 32 + l31];
            y[nt] = __builtin_amdgcn_mfma_f32_32x32x16_f16(a, b, y[nt], 0, 0, 0);
        }
    }

    float t1[16], t2[16];
    #pragma unroll
    for (int r = 0; r < 16; r++) { t1[r] = 0.0f; t2[r] = 0.0f; }
    #pragma unroll
    for (int nt = 0; nt < 2; nt++) {
        const int col = w * 64 + nt * 32 + l31;
        const float bias = nb2[col];
        #pragma unroll
        for (int r = 0; r < 16; r++) {
            const int node = n0 + (r & 3) + 8 * (r >> 2) + 4 * hh;
            const float v = y[nt][r] + bias + h[(size_t)node * H + col];
            y[nt][r] = v;
            t1[r] += v;
            t2[r] += v * v;
        }
    }
    #pragma unroll
    for (int m = 1; m < 32; m <<= 1) {
        #pragma unroll
        for (int r = 0; r < 16; r++) {
            t1[r] += __shfl_xor(t1[r], m);
            t2[r] += __shfl_xor(t2[r], m);
        }
    }
    if (l31 == 0) {
        #pragma unroll
        for (int r = 0; r < 16; r++) {
            const int row = (r & 3) + 8 * (r >> 2) + 4 * hh;
            atomicAdd(&s1[row], t1[r]);
            atomicAdd(&s2[row], t2[r]);
        }
    }
    __syncthreads();

    #pragma unroll
    for (int nt = 0; nt < 2; nt++) {
        const int col = w * 64 + nt * 32 + l31;
        const float g = lng[col];
        const float bb = lnb[col];
        #pragma unroll
        for (int r = 0; r < 16; r++) {
            const int row = (r & 3) + 8 * (r >> 2) + 4 * hh;
            const int node = n0 + row;
            const float mu = s1[row] * (1.0f / H);
            const float var = s2[row] * (1.0f / H) - mu * mu;
            const float rs = rsqrtf(var + LN_EPS);
            hout[(size_t)node * H + col] = (y[nt][r] - mu) * rs * g + bb;
        }
    }
}

extern "C" void kernel_launch(void* const* d_in, const int* in_sizes, int n_in,
                              void* d_out, int out_size, void* d_ws, size_t ws_size,
                              hipStream_t stream) {
    const float* h   = (const float*)d_in[0];
    const float* x   = (const float*)d_in[1];
    const int*   ei  = (const int*)d_in[2];
    const float* ew1 = (const float*)d_in[3];
    const float* eb1 = (const float*)d_in[4];
    const float* ew2 = (const float*)d_in[5];
    const float* eb2 = (const float*)d_in[6];
    const float* cw1 = (const float*)d_in[7];
    const float* cb1 = (const float*)d_in[8];
    const float* cw2 = (const float*)d_in[9];
    const float* nw1 = (const float*)d_in[10];
    const float* nb1 = (const float*)d_in[11];
    const float* nw2 = (const float*)d_in[12];
    const float* nb2 = (const float*)d_in[13];
    const float* lng = (const float*)d_in[14];
    const float* lnb = (const float*)d_in[15];

    float* hout = (float*)d_out;
    float* xout = hout + (size_t)NN * H;

    float* msg = (float*)d_ws;                              // NN*H f32
    int* bins = (int*)(msg + (size_t)NN * H);               // NN (memset)
    _Float16* P   = (_Float16*)(bins + NN);                 // NN*H f16
    _Float16* Qq  = P + (size_t)NN * H;                     // NN*H f16
    _Float16* Bp2 = Qq + (size_t)NN * H;                    // 256*256
    _Float16* Bp3 = Bp2 + 256 * 256;
    _Float16* BpB = Bp3 + 256 * 256;
    _Float16* BpA = BpB + 256 * 256;                        // 512*256
    _Float16* Bp1 = BpA + 512 * 256;                        // 256*512
    _Float16* wdh = Bp1 + 256 * 512;                        // 256
    int* cursor = (int*)(wdh + 256);
    int* perm   = cursor + NN;

    (void)hipMemsetAsync(bins, 0, (size_t)NN * 4, stream);
    k_misc<<<3376, 256, 0, stream>>>(ei, bins, x, xout, ew2, cw1, nw2, nw1, ew1,
                                     Bp2, Bp3, BpB, BpA, Bp1, wdh, msg);
    k_pre<<<NN / 32 + 1, 256, 0, stream>>>(h, Bp1, eb1, P, Qq, bins, cursor);
    k_scatter<<<(NE + 255) / 256, 256, 0, stream>>>(ei, cursor, perm);
    k_edge<<<NE / TE, 256, 0, stream>>>(x, ei, perm, P, Qq, wdh, Bp2, eb2,
                                        Bp3, cb1, cw2, msg, xout);
    k_node<<<NN / 32, 256, 0, stream>>>(h, msg, BpA, nb1, BpB, nb2,
                                        lng, lnb, hout);
}